// Round 6
// baseline (1753.939 us; speedup 1.0000x reference)
//
#include <hip/hip_runtime.h>
#include <hip/hip_bf16.h>
#include <math.h>

#define H 512
#define V 128
#define NLEAF 16384

typedef __attribute__((ext_vector_type(4))) float f32x4;
typedef __attribute__((ext_vector_type(8))) short s16x8;
typedef __attribute__((ext_vector_type(4))) unsigned short u16x4;
typedef unsigned short ushort_t;

// ---- static device scratch ----
__device__ ushort_t g_hb0[NLEAF * H];        // h bf16 (levels 14,12,...,0)
__device__ ushort_t g_hb1[(NLEAF / 2) * H];  // h bf16 (levels 13,11,...,1)
__device__ float    g_c0[NLEAF * H];         // c f32
__device__ float    g_c1[(NLEAF / 2) * H];
__device__ ushort_t g_UiouT[3 * H * 2 * H];  // [1536 cols][1024 k] bf16 (binary)
__device__ ushort_t g_UfT[H * 2 * H];        // [512 cols][1024 k] bf16 (f0|f1 halves)
__device__ ushort_t g_UiouTt[3 * H * 3 * H]; // [1536 cols][1536 k] bf16 (root)
__device__ ushort_t g_UfTt[H * 3 * H];       // [512 cols][1536 k] bf16 (f0|f1|f2)
__device__ float    g_rpart[3 * 3072];       // root k-chunk partials
__device__ float    g_root[2 * H];
__device__ float    g_hf[H];
__device__ float    g_gates[4 * H];
__device__ unsigned g_bar[64];               // grid-barrier cells (memset each call)

__device__ __forceinline__ float sigm(float x) { return 1.0f / (1.0f + __expf(-x)); }
__device__ __forceinline__ float ftanh(float x) {
  return 1.0f - 2.0f / (__expf(2.0f * x) + 1.0f);
}
__device__ __forceinline__ ushort_t f2bf(float x) {
  __hip_bfloat16 b = __float2bfloat16(x);
  return *reinterpret_cast<ushort_t*>(&b);
}
__device__ __forceinline__ float bf2f(ushort_t u) {
  union { unsigned int i; float f; } v; v.i = ((unsigned int)u) << 16; return v.f;
}
__device__ __forceinline__ void gload_lds16(const void* g, void* l) {
  __builtin_amdgcn_global_load_lds(
      (const __attribute__((address_space(1))) unsigned int*)g,
      (__attribute__((address_space(3))) unsigned int*)l, 16, 0, 0);
}

// grid barrier for the persistent tail kernel (all NB blocks co-resident).
#define TAIL_NB 256
__device__ __forceinline__ void gridbar(int idx) {
  __threadfence();                 // device-scope: flush this thread's writes
  __syncthreads();
  if (threadIdx.x == 0) {
    __hip_atomic_fetch_add(&g_bar[idx], 1u, __ATOMIC_ACQ_REL,
                           __HIP_MEMORY_SCOPE_AGENT);
    while (__hip_atomic_load(&g_bar[idx], __ATOMIC_ACQUIRE,
                             __HIP_MEMORY_SCOPE_AGENT) < TAIL_NB)
      __builtin_amdgcn_s_sleep(2);
  }
  __syncthreads();
}

// ---------------- weight transpose+convert: dst[c][r] = bf16(src[r][c]) ----
__global__ __launch_bounds__(256) void k_transp(const float* __restrict__ src,
                                                ushort_t* __restrict__ dst,
                                                int R, int Cc) {
  __shared__ float t[32][33];
  int bc = blockIdx.x * 32, br = blockIdx.y * 32;
  int tx = threadIdx.x & 31, ty = threadIdx.x >> 5;  // 32 x 8
  for (int rr = ty; rr < 32; rr += 8)
    t[rr][tx] = src[(size_t)(br + rr) * Cc + bc + tx];
  __syncthreads();
  for (int rr = ty; rr < 32; rr += 8)
    dst[(size_t)(bc + rr) * R + br + tx] = f2bf(t[tx][rr]);
}

// ---------------- leaf level (lvl 14): hk = ck = 0, pure elementwise -------
__global__ __launch_bounds__(256) void k_leaf(const int* __restrict__ tokens,
                                              const float* __restrict__ Wiou,
                                              const float* __restrict__ biou) {
  const int total = NLEAF * 128;                    // quads
  for (int q = blockIdx.x * 256 + threadIdx.x; q < total; q += gridDim.x * 256) {
    int i = q >> 7, jv = q & 127;                   // jv = j/4
    int tok = tokens[(NLEAF - 1) + i];
    const f32x4* Wr = (const f32x4*)(Wiou + (size_t)tok * 1536);
    const f32x4* bv = (const f32x4*)biou;
    f32x4 wi = Wr[jv] + bv[jv];
    f32x4 wo = Wr[128 + jv] + bv[128 + jv];
    f32x4 wu = Wr[256 + jv] + bv[256 + jv];
    u16x4 hv; f32x4 cv;
    #pragma unroll
    for (int r = 0; r < 4; ++r) {
      float c = sigm(wi[r]) * ftanh(wu[r]);
      float h = sigm(wo[r]) * ftanh(c);
      cv[r] = c;
      hv[r] = f2bf(h);
    }
    *reinterpret_cast<u16x4*>(&g_hb0[(size_t)q * 4]) = hv;
    *reinterpret_cast<f32x4*>(&g_c0[(size_t)q * 4]) = cv;
  }
}

// ---------------- big levels (n >= 256): MFMA bf16 fused cell --------------
// round-4 structure: 256 thr = 4 waves (2 row x 2 col), 128 nodes x 64 j.
__global__ __launch_bounds__(256, 2) void k_mfma_lvl(int lvl,
    const int* __restrict__ tokens,
    const float* __restrict__ Wiou, const float* __restrict__ biou,
    const float* __restrict__ Wf, const float* __restrict__ bf) {
  const int n = 1 << lvl;
  const int node0 = n - 1;
  const int outp = lvl & 1;
  const ushort_t* __restrict__ hprev = outp ? g_hb0 : g_hb1;
  const float* __restrict__ cprev = outp ? g_c0 : g_c1;
  ushort_t* __restrict__ hout = outp ? g_hb1 : g_hb0;
  float* __restrict__ cout = outp ? g_c1 : g_c0;

  const int i0 = blockIdx.x * 128;
  const int j0 = blockIdx.y * 64;
  const int tid = threadIdx.x;
  const int lane = tid & 63;
  const int w = tid >> 6;        // 0..3
  const int wry = w >> 1;        // row half
  const int cx = w & 1;          // col half

  __shared__ f32x4 smemv[3072];  // 48KB
  char* smem = (char*)smemv;

  const char* gp[6];
  unsigned lb[6], lstride[6];
  {
    int kb = (lane >> 4) * 16;
    #pragma unroll
    for (int q = 0; q < 6; ++q) {
      int c = w * 6 + q;
      if (c < 8) {               // A chunk, row-tile c
        int row = i0 + c * 16 + (lane & 15);
        gp[q] = (const char*)hprev + (size_t)row * 2048 + kb;
        lb[q] = c * 1024u;
        lstride[q] = 8192u;
      } else {                   // B chunk, col-tile ct
        int ct = c - 8;
        int col = ct * 16 + (lane & 15);
        int g = col >> 6, jj = j0 + (col & 63);
        const ushort_t* Ub = (g < 3) ? (g_UiouT + (size_t)(g * 512 + jj) * 1024)
                                     : (g_UfT + (size_t)jj * 1024);
        gp[q] = (const char*)Ub + kb;
        lb[q] = 16384u + ct * 1024u;
        lstride[q] = 16384u;
      }
    }
  }

#define STAGE(BUF)                                                   \
  {                                                                  \
    _Pragma("unroll")                                                \
    for (int q = 0; q < 6; ++q) {                                    \
      gload_lds16(gp[q], smem + lb[q] + (unsigned)(BUF) * lstride[q]); \
      gp[q] += 64;                                                   \
    }                                                                \
  }

  f32x4 acc[4][10];
  #pragma unroll
  for (int a = 0; a < 4; ++a)
    #pragma unroll
    for (int b = 0; b < 10; ++b) acc[a][b] = (f32x4){0.f, 0.f, 0.f, 0.f};

#define COMPUTE(FA)                                                          \
  {                                                                          \
    const char* ab = smem + buf * 8192 + wry * 4096 + lane * 16;             \
    s16x8 a0 = *(const s16x8*)(ab);                                          \
    s16x8 a1 = *(const s16x8*)(ab + 1024);                                   \
    s16x8 a2 = *(const s16x8*)(ab + 2048);                                   \
    s16x8 a3 = *(const s16x8*)(ab + 3072);                                   \
    const char* bb = smem + 16384 + buf * 16384 + cx * 2048 + lane * 16;     \
    s16x8 b0 = *(const s16x8*)(bb);                                          \
    s16x8 b1 = *(const s16x8*)(bb + 1024);                                   \
    s16x8 b2 = *(const s16x8*)(bb + 4096);                                   \
    s16x8 b3 = *(const s16x8*)(bb + 5120);                                   \
    s16x8 b4 = *(const s16x8*)(bb + 8192);                                   \
    s16x8 b5 = *(const s16x8*)(bb + 9216);                                   \
    s16x8 b6 = *(const s16x8*)(bb + 12288);                                  \
    s16x8 b7 = *(const s16x8*)(bb + 13312);                                  \
    s16x8 aa[4] = {a0, a1, a2, a3};                                          \
    _Pragma("unroll")                                                        \
    for (int rtl = 0; rtl < 4; ++rtl) {                                      \
      acc[rtl][0] = __builtin_amdgcn_mfma_f32_16x16x32_bf16(aa[rtl], b0, acc[rtl][0], 0, 0, 0); \
      acc[rtl][1] = __builtin_amdgcn_mfma_f32_16x16x32_bf16(aa[rtl], b1, acc[rtl][1], 0, 0, 0); \
      acc[rtl][2] = __builtin_amdgcn_mfma_f32_16x16x32_bf16(aa[rtl], b2, acc[rtl][2], 0, 0, 0); \
      acc[rtl][3] = __builtin_amdgcn_mfma_f32_16x16x32_bf16(aa[rtl], b3, acc[rtl][3], 0, 0, 0); \
      acc[rtl][4] = __builtin_amdgcn_mfma_f32_16x16x32_bf16(aa[rtl], b4, acc[rtl][4], 0, 0, 0); \
      acc[rtl][5] = __builtin_amdgcn_mfma_f32_16x16x32_bf16(aa[rtl], b5, acc[rtl][5], 0, 0, 0); \
      acc[rtl][FA] = __builtin_amdgcn_mfma_f32_16x16x32_bf16(aa[rtl], b6, acc[rtl][FA], 0, 0, 0); \
      acc[rtl][FA + 1] = __builtin_amdgcn_mfma_f32_16x16x32_bf16(aa[rtl], b7, acc[rtl][FA + 1], 0, 0, 0); \
    }                                                                        \
  }

  STAGE(0);
  __syncthreads();
  int buf = 0;
  for (int kt = 0; kt < 16; ++kt) {
    STAGE(buf ^ 1);
    COMPUTE(6);
    __syncthreads();
    buf ^= 1;
  }
  for (int kt = 16; kt < 32; ++kt) {
    if (kt < 31) STAGE(buf ^ 1);
    COMPUTE(8);
    __syncthreads();
    buf ^= 1;
  }
#undef COMPUTE
#undef STAGE

  const int node_c = lane >> 4;
  const int jl = lane & 15;
  #pragma unroll
  for (int t = 0; t < 2; ++t) {
    const int j = j0 + cx * 32 + t * 16 + jl;
    const float bi = biou[j], bo = biou[512 + j], bu = biou[1024 + j], bfv = bf[j];
    #pragma unroll
    for (int rtl = 0; rtl < 4; ++rtl) {
      f32x4 vi = acc[rtl][0 + t], vo = acc[rtl][2 + t], vu = acc[rtl][4 + t],
            v0 = acc[rtl][6 + t], v1 = acc[rtl][8 + t];
      const int ib = i0 + wry * 64 + rtl * 16 + node_c * 4;
      #pragma unroll
      for (int r = 0; r < 4; ++r) {
        int i = ib + r;
        int tok = tokens[node0 + i];
        const float* Wr = Wiou + (size_t)tok * 1536;
        float fpre = Wf[(size_t)tok * 512 + j] + bfv;
        float ig = vi[r] + Wr[j] + bi;
        float og = vo[r] + Wr[512 + j] + bo;
        float ug = vu[r] + Wr[1024 + j] + bu;
        float cc = sigm(ig) * ftanh(ug)
                 + sigm(fpre + v0[r]) * cprev[(size_t)(2 * i) * 512 + j]
                 + sigm(fpre + v1[r]) * cprev[(size_t)(2 * i + 1) * 512 + j];
        float hh = sigm(og) * ftanh(cc);
        hout[(size_t)i * 512 + j] = f2bf(hh);
        cout[(size_t)i * 512 + j] = cc;
      }
    }
  }
}

// ---------------- persistent tail: levels 7..0 + root + heads --------------
__global__ __launch_bounds__(256, 1) void k_tail(
    const int* __restrict__ tokens,
    const float* __restrict__ Wiou, const float* __restrict__ biou,
    const float* __restrict__ Wf, const float* __restrict__ bf,
    const float* __restrict__ Wiou_t, const float* __restrict__ biou_t,
    const float* __restrict__ Wf_t, const float* __restrict__ bf_t,
    const float* __restrict__ ffnW, const float* __restrict__ ffnb,
    const float* __restrict__ Wx, const float* __restrict__ lb,
    const float* __restrict__ vm,
    const float* __restrict__ hlW, const float* __restrict__ hlb,
    const float* __restrict__ intW, const float* __restrict__ intb,
    const float* __restrict__ actW, const float* __restrict__ actb,
    float* __restrict__ out) {
  __shared__ float hl[1024];
  __shared__ float exch[5][64];
  const int b = blockIdx.x;
  const int tid = threadIdx.x;
  int barid = 0;

  // ---- levels 7..0 (GEMV tasks: task = node*8 + jb) ----
  for (int lvl = 7; lvl >= 0; --lvl) {
    const int n = 1 << lvl;
    const int node0 = n - 1;
    const int outp = lvl & 1;
    const ushort_t* __restrict__ hprev = outp ? g_hb0 : g_hb1;
    const float* __restrict__ cprev = outp ? g_c0 : g_c1;
    ushort_t* __restrict__ hout = outp ? g_hb1 : g_hb0;
    float* __restrict__ cout = outp ? g_c1 : g_c0;
    const int tasks = 8 * n;
    for (int t = b; t < tasks; t += TAIL_NB) {
      const int i = t >> 3;
      const int j0 = (t & 7) * 64;
      const int g = tid >> 6;
      const int jc = tid & 63;
      const int jj = j0 + jc;
      __syncthreads();
      for (int q = tid; q < 1024; q += 256)
        hl[q] = bf2f(hprev[(size_t)i * 1024 + q]);
      __syncthreads();

      const ushort_t* col = (g < 3) ? (g_UiouT + (size_t)(g * 512 + jj) * 1024)
                                    : (g_UfT + (size_t)jj * 1024);
      float a0 = 0.f, a1 = 0.f;
      #pragma unroll 4
      for (int k0 = 0; k0 < 512; k0 += 8) {
        s16x8 wv = *(const s16x8*)(col + k0);
        #pragma unroll
        for (int r = 0; r < 8; ++r) a0 += hl[k0 + r] * bf2f((ushort_t)wv[r]);
      }
      #pragma unroll 4
      for (int k0 = 512; k0 < 1024; k0 += 8) {
        s16x8 wv = *(const s16x8*)(col + k0);
        #pragma unroll
        for (int r = 0; r < 8; ++r) a1 += hl[k0 + r] * bf2f((ushort_t)wv[r]);
      }
      if (g < 3) exch[g][jc] = a0 + a1;
      else { exch[3][jc] = a0; exch[4][jc] = a1; }
      __syncthreads();

      if (tid < 64) {
        int j = j0 + tid;
        float ai = exch[0][tid], ao = exch[1][tid], au = exch[2][tid];
        float af0 = exch[3][tid], af1 = exch[4][tid];
        int tok = tokens[node0 + i];
        const float* Wr = Wiou + (size_t)tok * 1536;
        float fpre = Wf[(size_t)tok * 512 + j] + bf[j];
        float ig = ai + Wr[j] + biou[j];
        float og = ao + Wr[512 + j] + biou[512 + j];
        float ug = au + Wr[1024 + j] + biou[1024 + j];
        float cc = sigm(ig) * ftanh(ug)
                 + sigm(fpre + af0) * cprev[(size_t)(2 * i) * 512 + j]
                 + sigm(fpre + af1) * cprev[(size_t)(2 * i + 1) * 512 + j];
        float hh = sigm(og) * ftanh(cc);
        hout[(size_t)i * 512 + j] = f2bf(hh);
        cout[(size_t)i * 512 + j] = cc;
      }
    }
    gridbar(barid++);
  }

  // ---- root phase 1: 36 tasks (12 c-chunks x 3 k-thirds) ----
  if (b < 36) {
    const int by = b / 12;
    const int cc = (b % 12) * 256 + tid;
    __syncthreads();
    {
      int m0 = by * 512;
      for (int q = tid; q < 512; q += 256) {
        int m = m0 + q;
        hl[q] = (m < 512) ? bf2f(g_hb0[m]) : bf2f(g_hb1[m - 512]);
      }
    }
    __syncthreads();
    float acc = 0.f;
    const ushort_t* col = nullptr;
    if (cc < 1536) {
      col = g_UiouTt + (size_t)cc * 1536 + by * 512;
    } else {
      int v = cc - 1536;
      if ((v >> 9) == by) col = g_UfTt + (size_t)(v & 511) * 1536 + by * 512;
    }
    if (col) {
      #pragma unroll 4
      for (int k0 = 0; k0 < 512; k0 += 8) {
        s16x8 wv = *(const s16x8*)(col + k0);
        #pragma unroll
        for (int r = 0; r < 8; ++r) acc += hl[k0 + r] * bf2f((ushort_t)wv[r]);
      }
    }
    g_rpart[(size_t)by * 3072 + cc] = acc;
  }
  gridbar(barid++);

  // ---- root phase 2 (elementwise over j; 2 blocks) ----
  if (b < 2) {
    int j = b * 256 + tid;
    float ai = g_rpart[j] + g_rpart[3072 + j] + g_rpart[6144 + j];
    float ao = g_rpart[512 + j] + g_rpart[3072 + 512 + j] + g_rpart[6144 + 512 + j];
    float au = g_rpart[1024 + j] + g_rpart[3072 + 1024 + j] + g_rpart[6144 + 1024 + j];
    float f0 = g_rpart[1536 + j] + g_rpart[3072 + 1536 + j] + g_rpart[6144 + 1536 + j];
    float f1 = g_rpart[2048 + j] + g_rpart[3072 + 2048 + j] + g_rpart[6144 + 2048 + j];
    float f2 = g_rpart[2560 + j] + g_rpart[3072 + 2560 + j] + g_rpart[6144 + 2560 + j];
    int tok = tokens[0];
    float fpre = Wf_t[(size_t)tok * 512 + j] + bf_t[j];
    float ig = ai + Wiou_t[(size_t)tok * 1536 + j] + biou_t[j];
    float og = ao + Wiou_t[(size_t)tok * 1536 + 512 + j] + biou_t[512 + j];
    float ug = au + Wiou_t[(size_t)tok * 1536 + 1024 + j] + biou_t[1024 + j];
    float cc = sigm(ig) * ftanh(ug)
             + sigm(fpre + f0) * g_c0[j]
             + sigm(fpre + f1) * g_c1[j]
             + sigm(fpre + f2) * g_c1[512 + j];
    float hh = sigm(og) * ftanh(cc);
    g_root[j] = hh;
    g_root[512 + j] = cc;
  }
  gridbar(barid++);

  // ---- head1: FFN + relu (2 blocks) ----
  if (b < 2) {
    int j = b * 256 + tid;
    __syncthreads();
    for (int q = tid; q < 512; q += 256) hl[q] = g_root[q];
    __syncthreads();
    float acc = ffnb[j];
    #pragma unroll 8
    for (int m = 0; m < 512; ++m) acc += hl[m] * ffnW[m * 512 + j];
    g_hf[j] = fmaxf(acc, 0.0f);
  }
  gridbar(barid++);

  // ---- head2: LSTM gates (8 blocks) ----
  if (b < 8) {
    int g2 = b * 256 + tid;
    __syncthreads();
    for (int q = tid; q < 512; q += 256) hl[q] = g_hf[q];
    __syncthreads();
    float acc = lb[g2];
    #pragma unroll 8
    for (int m = 0; m < 512; ++m) acc += hl[m] * Wx[m * 2048 + g2];
    g_gates[g2] = acc;  // h_g starts at 0 so Wh term vanishes
  }
  gridbar(barid++);

  // ---- head3: final heads (block 0, 4 waves) ----
  if (b == 0) {
    #pragma unroll
    for (int q = 0; q < 2; ++q) {
      int j = tid + q * 256;
      float ci = sigm(g_gates[j]) * ftanh(g_gates[1024 + j]);
      float hg = sigm(g_gates[1536 + j]) * ftanh(ci);
      hl[j] = g_hf[j];
      hl[512 + j] = hg;
    }
    __syncthreads();
    const int wv = tid >> 6;
    const int lane = tid & 63;
    for (int o = wv; o < 43; o += 4) {
      const float* Wc;
      int stride, colb;
      if (o < 2)       { Wc = hlW;  stride = 2;  colb = o; }
      else if (o < 7)  { Wc = intW; stride = 5;  colb = o - 2; }
      else             { Wc = actW; stride = 36; colb = o - 7; }
      float s = 0.f;
      #pragma unroll
      for (int q = 0; q < 16; ++q) {
        int m = lane + q * 64;
        s += hl[m] * Wc[(size_t)m * stride + colb];
      }
      #pragma unroll
      for (int d = 32; d >= 1; d >>= 1) s += __shfl_xor(s, d);
      if (lane == 0) {
        float res;
        if (o < 2)      res = s + hlb[o];
        else if (o < 7) res = s + intb[o - 2];
        else {
          int a = o - 7;
          float v = vm[a];
          res = __logf(v) + s * v + actb[a] * v;
        }
        out[o] = res;
      }
    }
  }
}

extern "C" void kernel_launch(void* const* d_in, const int* in_sizes, int n_in,
                              void* d_out, int out_size, void* d_ws, size_t ws_size,
                              hipStream_t stream) {
  (void)in_sizes; (void)n_in; (void)d_ws; (void)ws_size; (void)out_size;
  const int* tokens   = (const int*)d_in[0];
  const float* vm     = (const float*)d_in[1];
  const float* Wiou_b = (const float*)d_in[2];
  const float* Uiou_b = (const float*)d_in[3];
  const float* biou_b = (const float*)d_in[4];
  const float* Wf_b   = (const float*)d_in[5];
  const float* Uf_b   = (const float*)d_in[6];
  const float* bf_b   = (const float*)d_in[7];
  const float* Wiou_t = (const float*)d_in[8];
  const float* Uiou_t = (const float*)d_in[9];
  const float* biou_t = (const float*)d_in[10];
  const float* Wf_t   = (const float*)d_in[11];
  const float* Uf_t   = (const float*)d_in[12];
  const float* bf_t   = (const float*)d_in[13];
  const float* ffnW   = (const float*)d_in[14];
  const float* ffnb   = (const float*)d_in[15];
  const float* lstmWx = (const float*)d_in[16];
  const float* lstmb  = (const float*)d_in[18];
  const float* hlW    = (const float*)d_in[19];
  const float* hlb    = (const float*)d_in[20];
  const float* intW   = (const float*)d_in[21];
  const float* intb   = (const float*)d_in[22];
  const float* actW   = (const float*)d_in[23];
  const float* actb   = (const float*)d_in[24];

  ushort_t* UiouT;  hipGetSymbolAddress((void**)&UiouT, HIP_SYMBOL(g_UiouT));
  ushort_t* UfT;    hipGetSymbolAddress((void**)&UfT, HIP_SYMBOL(g_UfT));
  ushort_t* UiouTt; hipGetSymbolAddress((void**)&UiouTt, HIP_SYMBOL(g_UiouTt));
  ushort_t* UfTt;   hipGetSymbolAddress((void**)&UfTt, HIP_SYMBOL(g_UfTt));
  unsigned* barp;   hipGetSymbolAddress((void**)&barp, HIP_SYMBOL(g_bar));

  hipMemsetAsync(barp, 0, 64 * sizeof(unsigned), stream);

  // weight transpose+bf16 convert (every call; deterministic)
  k_transp<<<dim3(48, 32), 256, 0, stream>>>(Uiou_b, UiouT, 1024, 1536);
  k_transp<<<dim3(16, 32), 256, 0, stream>>>(Uf_b, UfT, 1024, 512);
  k_transp<<<dim3(48, 48), 256, 0, stream>>>(Uiou_t, UiouTt, 1536, 1536);
  k_transp<<<dim3(16, 48), 256, 0, stream>>>(Uf_t, UfTt, 1536, 512);

  k_leaf<<<2048, 256, 0, stream>>>(tokens, Wiou_b, biou_b);
  for (int lvl = 13; lvl >= 8; --lvl) {
    int gx = (1 << lvl) / 128;
    k_mfma_lvl<<<dim3(gx, 8), 256, 0, stream>>>(lvl, tokens, Wiou_b, biou_b,
                                                Wf_b, bf_b);
  }
  k_tail<<<TAIL_NB, 256, 0, stream>>>(tokens, Wiou_b, biou_b, Wf_b, bf_b,
                                      Wiou_t, biou_t, Wf_t, bf_t,
                                      ffnW, ffnb, lstmWx, lstmb, vm,
                                      hlW, hlb, intW, intb, actW, actb,
                                      (float*)d_out);
}

// Round 7
// 658.641 us; speedup vs baseline: 2.6630x; 2.6630x over previous
//
#include <hip/hip_runtime.h>
#include <hip/hip_bf16.h>
#include <math.h>

#define H 512
#define V 128
#define NLEAF 16384

typedef __attribute__((ext_vector_type(4))) float f32x4;
typedef __attribute__((ext_vector_type(8))) short s16x8;
typedef __attribute__((ext_vector_type(4))) unsigned short u16x4;
typedef unsigned short ushort_t;

// ---- static device scratch ----
__device__ ushort_t g_hb0[NLEAF * H];        // h bf16 (levels 14,12,...,0)
__device__ ushort_t g_hb1[(NLEAF / 2) * H];  // h bf16 (levels 13,11,...,1)
__device__ float    g_c0[NLEAF * H];         // c f32
__device__ float    g_c1[(NLEAF / 2) * H];
__device__ ushort_t g_UiouT[3 * H * 2 * H];  // [1536 cols][1024 k] bf16 (binary)
__device__ ushort_t g_UfT[H * 2 * H];        // [512 cols][1024 k] bf16 (f0|f1 halves)
__device__ ushort_t g_UiouTt[3 * H * 3 * H]; // [1536 cols][1536 k] bf16 (root)
__device__ ushort_t g_UfTt[H * 3 * H];       // [512 cols][1536 k] bf16 (f0|f1|f2)
__device__ float    g_rpart[3 * 3072];       // root k-chunk partials
__device__ float    g_root[2 * H];
__device__ float    g_hf[H];
__device__ float    g_gates[4 * H];

__device__ __forceinline__ float sigm(float x) { return 1.0f / (1.0f + __expf(-x)); }
__device__ __forceinline__ float ftanh(float x) {
  return 1.0f - 2.0f / (__expf(2.0f * x) + 1.0f);
}
__device__ __forceinline__ ushort_t f2bf(float x) {
  __hip_bfloat16 b = __float2bfloat16(x);
  return *reinterpret_cast<ushort_t*>(&b);
}
__device__ __forceinline__ float bf2f(ushort_t u) {
  union { unsigned int i; float f; } v; v.i = ((unsigned int)u) << 16; return v.f;
}
__device__ __forceinline__ void gload_lds16(const void* g, void* l) {
  __builtin_amdgcn_global_load_lds(
      (const __attribute__((address_space(1))) unsigned int*)g,
      (__attribute__((address_space(3))) unsigned int*)l, 16, 0, 0);
}

// ------- merged weight transpose+convert: 4 matrices in one launch --------
// z selects: 0 Uiou_b(1024x1536), 1 Uf_b(1024x512), 2 Uiou_t(1536x1536),
// 3 Uf_t(1536x512). dst[c][r] = bf16(src[r][c]).
__global__ __launch_bounds__(256) void k_transp_all(
    const float* __restrict__ s0, const float* __restrict__ s1,
    const float* __restrict__ s2, const float* __restrict__ s3,
    ushort_t* __restrict__ d0, ushort_t* __restrict__ d1,
    ushort_t* __restrict__ d2, ushort_t* __restrict__ d3) {
  const float* src; ushort_t* dst; int R, Cc;
  switch (blockIdx.z) {
    case 0: src = s0; dst = d0; R = 1024; Cc = 1536; break;
    case 1: src = s1; dst = d1; R = 1024; Cc = 512; break;
    case 2: src = s2; dst = d2; R = 1536; Cc = 1536; break;
    default: src = s3; dst = d3; R = 1536; Cc = 512; break;
  }
  int bc = blockIdx.x * 32, br = blockIdx.y * 32;
  if (bc >= Cc || br >= R) return;
  __shared__ float t[32][33];
  int tx = threadIdx.x & 31, ty = threadIdx.x >> 5;  // 32 x 8
  for (int rr = ty; rr < 32; rr += 8)
    t[rr][tx] = src[(size_t)(br + rr) * Cc + bc + tx];
  __syncthreads();
  for (int rr = ty; rr < 32; rr += 8)
    dst[(size_t)(bc + rr) * R + br + tx] = f2bf(t[tx][rr]);
}

// ---------------- leaf level (lvl 14): hk = ck = 0, pure elementwise -------
__global__ __launch_bounds__(256) void k_leaf(const int* __restrict__ tokens,
                                              const float* __restrict__ Wiou,
                                              const float* __restrict__ biou) {
  const int total = NLEAF * 128;                    // quads
  for (int q = blockIdx.x * 256 + threadIdx.x; q < total; q += gridDim.x * 256) {
    int i = q >> 7, jv = q & 127;                   // jv = j/4
    int tok = tokens[(NLEAF - 1) + i];
    const f32x4* Wr = (const f32x4*)(Wiou + (size_t)tok * 1536);
    const f32x4* bv = (const f32x4*)biou;
    f32x4 wi = Wr[jv] + bv[jv];
    f32x4 wo = Wr[128 + jv] + bv[128 + jv];
    f32x4 wu = Wr[256 + jv] + bv[256 + jv];
    u16x4 hv; f32x4 cv;
    #pragma unroll
    for (int r = 0; r < 4; ++r) {
      float c = sigm(wi[r]) * ftanh(wu[r]);
      float h = sigm(wo[r]) * ftanh(c);
      cv[r] = c;
      hv[r] = f2bf(h);
    }
    *reinterpret_cast<u16x4*>(&g_hb0[(size_t)q * 4]) = hv;
    *reinterpret_cast<f32x4*>(&g_c0[(size_t)q * 4]) = cv;
  }
}

// ---------------- big levels (n >= 256): MFMA bf16 fused cell --------------
// 256 thr = 4 waves (2 row x 2 col). Tile: 128 nodes x 64 j-cols x 5 gates.
__global__ __launch_bounds__(256, 2) void k_mfma_lvl(int lvl,
    const int* __restrict__ tokens,
    const float* __restrict__ Wiou, const float* __restrict__ biou,
    const float* __restrict__ Wf, const float* __restrict__ bf) {
  const int n = 1 << lvl;
  const int node0 = n - 1;
  const int outp = lvl & 1;
  const ushort_t* __restrict__ hprev = outp ? g_hb0 : g_hb1;
  const float* __restrict__ cprev = outp ? g_c0 : g_c1;
  ushort_t* __restrict__ hout = outp ? g_hb1 : g_hb0;
  float* __restrict__ cout = outp ? g_c1 : g_c0;

  const int i0 = blockIdx.x * 128;
  const int j0 = blockIdx.y * 64;
  const int tid = threadIdx.x;
  const int lane = tid & 63;
  const int w = tid >> 6;        // 0..3
  const int wry = w >> 1;        // row half
  const int cx = w & 1;          // col half

  __shared__ f32x4 smemv[3072];  // 48KB
  char* smem = (char*)smemv;

  const char* gp[6];
  unsigned lb[6], lstride[6];
  {
    int kb = (lane >> 4) * 16;
    #pragma unroll
    for (int q = 0; q < 6; ++q) {
      int c = w * 6 + q;
      if (c < 8) {               // A chunk, row-tile c
        int row = i0 + c * 16 + (lane & 15);
        gp[q] = (const char*)hprev + (size_t)row * 2048 + kb;
        lb[q] = c * 1024u;
        lstride[q] = 8192u;
      } else {                   // B chunk, col-tile ct
        int ct = c - 8;
        int col = ct * 16 + (lane & 15);
        int g = col >> 6, jj = j0 + (col & 63);
        const ushort_t* Ub = (g < 3) ? (g_UiouT + (size_t)(g * 512 + jj) * 1024)
                                     : (g_UfT + (size_t)jj * 1024);
        gp[q] = (const char*)Ub + kb;
        lb[q] = 16384u + ct * 1024u;
        lstride[q] = 16384u;
      }
    }
  }

#define STAGE(BUF)                                                   \
  {                                                                  \
    _Pragma("unroll")                                                \
    for (int q = 0; q < 6; ++q) {                                    \
      gload_lds16(gp[q], smem + lb[q] + (unsigned)(BUF) * lstride[q]); \
      gp[q] += 64;                                                   \
    }                                                                \
  }

  f32x4 acc[4][10];
  #pragma unroll
  for (int a = 0; a < 4; ++a)
    #pragma unroll
    for (int b = 0; b < 10; ++b) acc[a][b] = (f32x4){0.f, 0.f, 0.f, 0.f};

#define COMPUTE(FA)                                                          \
  {                                                                          \
    const char* ab = smem + buf * 8192 + wry * 4096 + lane * 16;             \
    s16x8 a0 = *(const s16x8*)(ab);                                          \
    s16x8 a1 = *(const s16x8*)(ab + 1024);                                   \
    s16x8 a2 = *(const s16x8*)(ab + 2048);                                   \
    s16x8 a3 = *(const s16x8*)(ab + 3072);                                   \
    const char* bb = smem + 16384 + buf * 16384 + cx * 2048 + lane * 16;     \
    s16x8 b0 = *(const s16x8*)(bb);                                          \
    s16x8 b1 = *(const s16x8*)(bb + 1024);                                   \
    s16x8 b2 = *(const s16x8*)(bb + 4096);                                   \
    s16x8 b3 = *(const s16x8*)(bb + 5120);                                   \
    s16x8 b4 = *(const s16x8*)(bb + 8192);                                   \
    s16x8 b5 = *(const s16x8*)(bb + 9216);                                   \
    s16x8 b6 = *(const s16x8*)(bb + 12288);                                  \
    s16x8 b7 = *(const s16x8*)(bb + 13312);                                  \
    s16x8 aa[4] = {a0, a1, a2, a3};                                          \
    _Pragma("unroll")                                                        \
    for (int rtl = 0; rtl < 4; ++rtl) {                                      \
      acc[rtl][0] = __builtin_amdgcn_mfma_f32_16x16x32_bf16(aa[rtl], b0, acc[rtl][0], 0, 0, 0); \
      acc[rtl][1] = __builtin_amdgcn_mfma_f32_16x16x32_bf16(aa[rtl], b1, acc[rtl][1], 0, 0, 0); \
      acc[rtl][2] = __builtin_amdgcn_mfma_f32_16x16x32_bf16(aa[rtl], b2, acc[rtl][2], 0, 0, 0); \
      acc[rtl][3] = __builtin_amdgcn_mfma_f32_16x16x32_bf16(aa[rtl], b3, acc[rtl][3], 0, 0, 0); \
      acc[rtl][4] = __builtin_amdgcn_mfma_f32_16x16x32_bf16(aa[rtl], b4, acc[rtl][4], 0, 0, 0); \
      acc[rtl][5] = __builtin_amdgcn_mfma_f32_16x16x32_bf16(aa[rtl], b5, acc[rtl][5], 0, 0, 0); \
      acc[rtl][FA] = __builtin_amdgcn_mfma_f32_16x16x32_bf16(aa[rtl], b6, acc[rtl][FA], 0, 0, 0); \
      acc[rtl][FA + 1] = __builtin_amdgcn_mfma_f32_16x16x32_bf16(aa[rtl], b7, acc[rtl][FA + 1], 0, 0, 0); \
    }                                                                        \
  }

  STAGE(0);
  __syncthreads();
  int buf = 0;
  for (int kt = 0; kt < 16; ++kt) {
    STAGE(buf ^ 1);
    COMPUTE(6);
    __syncthreads();
    buf ^= 1;
  }
  for (int kt = 16; kt < 32; ++kt) {
    if (kt < 31) STAGE(buf ^ 1);
    COMPUTE(8);
    __syncthreads();
    buf ^= 1;
  }
#undef COMPUTE
#undef STAGE

  const int node_c = lane >> 4;
  const int jl = lane & 15;
  #pragma unroll
  for (int t = 0; t < 2; ++t) {
    const int j = j0 + cx * 32 + t * 16 + jl;
    const float bi = biou[j], bo = biou[512 + j], bu = biou[1024 + j], bfv = bf[j];
    #pragma unroll
    for (int rtl = 0; rtl < 4; ++rtl) {
      f32x4 vi = acc[rtl][0 + t], vo = acc[rtl][2 + t], vu = acc[rtl][4 + t],
            v0 = acc[rtl][6 + t], v1 = acc[rtl][8 + t];
      const int ib = i0 + wry * 64 + rtl * 16 + node_c * 4;
      #pragma unroll
      for (int r = 0; r < 4; ++r) {
        int i = ib + r;
        int tok = tokens[node0 + i];
        const float* Wr = Wiou + (size_t)tok * 1536;
        float fpre = Wf[(size_t)tok * 512 + j] + bfv;
        float ig = vi[r] + Wr[j] + bi;
        float og = vo[r] + Wr[512 + j] + bo;
        float ug = vu[r] + Wr[1024 + j] + bu;
        float cc = sigm(ig) * ftanh(ug)
                 + sigm(fpre + v0[r]) * cprev[(size_t)(2 * i) * 512 + j]
                 + sigm(fpre + v1[r]) * cprev[(size_t)(2 * i + 1) * 512 + j];
        float hh = sigm(og) * ftanh(cc);
        hout[(size_t)i * 512 + j] = f2bf(hh);
        cout[(size_t)i * 512 + j] = cc;
      }
    }
  }
}

// ------------- small levels (n <= 128): single fused GEMV kernel -----------
__global__ __launch_bounds__(256) void k_small(int lvl,
    const int* __restrict__ tokens,
    const float* __restrict__ Wiou, const float* __restrict__ biou,
    const float* __restrict__ Wf, const float* __restrict__ bf) {
  const int n = 1 << lvl;
  const int node0 = n - 1;
  const int outp = lvl & 1;
  const ushort_t* __restrict__ hprev = outp ? g_hb0 : g_hb1;
  const float* __restrict__ cprev = outp ? g_c0 : g_c1;
  ushort_t* __restrict__ hout = outp ? g_hb1 : g_hb0;
  float* __restrict__ cout = outp ? g_c1 : g_c0;

  const int i = blockIdx.y;
  const int j0 = blockIdx.x * 64;
  const int tid = threadIdx.x;
  const int g = tid >> 6;
  const int jc = tid & 63;
  const int jj = j0 + jc;

  __shared__ float hl[1024];
  __shared__ float exch[5][64];
  for (int t = tid; t < 1024; t += 256) hl[t] = bf2f(hprev[(size_t)i * 1024 + t]);
  __syncthreads();

  const ushort_t* col = (g < 3) ? (g_UiouT + (size_t)(g * 512 + jj) * 1024)
                                : (g_UfT + (size_t)jj * 1024);
  float a0 = 0.f, a1 = 0.f;
  #pragma unroll 4
  for (int k0 = 0; k0 < 512; k0 += 8) {
    s16x8 wv = *(const s16x8*)(col + k0);
    #pragma unroll
    for (int r = 0; r < 8; ++r) a0 += hl[k0 + r] * bf2f((ushort_t)wv[r]);
  }
  #pragma unroll 4
  for (int k0 = 512; k0 < 1024; k0 += 8) {
    s16x8 wv = *(const s16x8*)(col + k0);
    #pragma unroll
    for (int r = 0; r < 8; ++r) a1 += hl[k0 + r] * bf2f((ushort_t)wv[r]);
  }
  if (g < 3) exch[g][jc] = a0 + a1;
  else { exch[3][jc] = a0; exch[4][jc] = a1; }
  __syncthreads();

  if (tid < 64) {
    int j = j0 + tid;
    float ai = exch[0][tid], ao = exch[1][tid], au = exch[2][tid];
    float af0 = exch[3][tid], af1 = exch[4][tid];
    int tok = tokens[node0 + i];
    const float* Wr = Wiou + (size_t)tok * 1536;
    float fpre = Wf[(size_t)tok * 512 + j] + bf[j];
    float ig = ai + Wr[j] + biou[j];
    float og = ao + Wr[512 + j] + biou[512 + j];
    float ug = au + Wr[1024 + j] + biou[1024 + j];
    float cc = sigm(ig) * ftanh(ug)
             + sigm(fpre + af0) * cprev[(size_t)(2 * i) * 512 + j]
             + sigm(fpre + af1) * cprev[(size_t)(2 * i + 1) * 512 + j];
    float hh = sigm(og) * ftanh(cc);
    hout[(size_t)i * 512 + j] = f2bf(hh);
    cout[(size_t)i * 512 + j] = cc;
  }
}

// ---------------- root ternary cell: 2-phase k-split -----------------------
__global__ __launch_bounds__(256) void k_root_p1() {
  const int by = blockIdx.y;
  const int tid = threadIdx.x;
  const int c = blockIdx.x * 256 + tid;      // 0..3071

  __shared__ float hl[512];
  {
    int m0 = by * 512;
    #pragma unroll
    for (int q = 0; q < 2; ++q) {
      int t = tid + q * 256, m = m0 + t;
      hl[t] = (m < 512) ? bf2f(g_hb0[m]) : bf2f(g_hb1[m - 512]);
    }
  }
  __syncthreads();

  float acc = 0.f;
  const ushort_t* col = nullptr;
  if (c < 1536) {
    col = g_UiouTt + (size_t)c * 1536 + by * 512;
  } else {
    int v = c - 1536;
    if ((v >> 9) == by) col = g_UfTt + (size_t)(v & 511) * 1536 + by * 512;
  }
  if (col) {
    #pragma unroll 4
    for (int k0 = 0; k0 < 512; k0 += 8) {
      s16x8 wv = *(const s16x8*)(col + k0);
      #pragma unroll
      for (int r = 0; r < 8; ++r) acc += hl[k0 + r] * bf2f((ushort_t)wv[r]);
    }
  }
  g_rpart[(size_t)by * 3072 + c] = acc;
}

__global__ __launch_bounds__(512) void k_root_p2(const int* __restrict__ tokens,
    const float* __restrict__ Wiou_t, const float* __restrict__ biou_t,
    const float* __restrict__ Wf_t, const float* __restrict__ bf_t) {
  const int j = threadIdx.x;
  float ai = g_rpart[j] + g_rpart[3072 + j] + g_rpart[6144 + j];
  float ao = g_rpart[512 + j] + g_rpart[3072 + 512 + j] + g_rpart[6144 + 512 + j];
  float au = g_rpart[1024 + j] + g_rpart[3072 + 1024 + j] + g_rpart[6144 + 1024 + j];
  float f0 = g_rpart[1536 + j] + g_rpart[3072 + 1536 + j] + g_rpart[6144 + 1536 + j];
  float f1 = g_rpart[2048 + j] + g_rpart[3072 + 2048 + j] + g_rpart[6144 + 2048 + j];
  float f2 = g_rpart[2560 + j] + g_rpart[3072 + 2560 + j] + g_rpart[6144 + 2560 + j];

  int tok = tokens[0];
  float fpre = Wf_t[(size_t)tok * H + j] + bf_t[j];
  float ig = ai + Wiou_t[(size_t)tok * 3 * H + j] + biou_t[j];
  float og = ao + Wiou_t[(size_t)tok * 3 * H + H + j] + biou_t[H + j];
  float ug = au + Wiou_t[(size_t)tok * 3 * H + 2 * H + j] + biou_t[2 * H + j];
  float cc = sigm(ig) * ftanh(ug)
           + sigm(fpre + f0) * g_c0[j]
           + sigm(fpre + f1) * g_c1[j]
           + sigm(fpre + f2) * g_c1[H + j];
  float hh = sigm(og) * ftanh(cc);
  g_root[j] = hh;
  g_root[H + j] = cc;
}

// ---------------- heads ----------------------------------------------------
__global__ __launch_bounds__(512) void k_head1(const float* __restrict__ ffnW,
                                               const float* __restrict__ ffnb) {
  __shared__ float hr[H];
  int j = threadIdx.x;
  hr[j] = g_root[j];
  __syncthreads();
  float acc = ffnb[j];
  #pragma unroll 8
  for (int m = 0; m < H; ++m) acc += hr[m] * ffnW[m * H + j];
  g_hf[j] = fmaxf(acc, 0.0f);
}

__global__ __launch_bounds__(64) void k_head2(const float* __restrict__ Wx,
                                              const float* __restrict__ lb) {
  int g = blockIdx.x * 64 + threadIdx.x;
  float acc = lb[g];
  #pragma unroll 8
  for (int m = 0; m < H; ++m) acc += g_hf[m] * Wx[m * 4 * H + g];
  g_gates[g] = acc;  // h_g starts at 0 so Wh term vanishes
}

__global__ __launch_bounds__(512) void k_head3(const float* __restrict__ vm,
    const float* __restrict__ hlW, const float* __restrict__ hlb,
    const float* __restrict__ intW, const float* __restrict__ intb,
    const float* __restrict__ actW, const float* __restrict__ actb,
    float* __restrict__ out) {
  __shared__ float feat[2 * H];
  int j = threadIdx.x;
  float ci = sigm(g_gates[j]) * ftanh(g_gates[2 * H + j]);
  float hg = sigm(g_gates[3 * H + j]) * ftanh(ci);
  feat[j] = g_hf[j];
  feat[H + j] = hg;
  __syncthreads();

  const int wv = threadIdx.x >> 6;
  const int lane = threadIdx.x & 63;
  for (int o = wv; o < 43; o += 8) {
    const float* Wc;
    int stride, colb;
    if (o < 2)       { Wc = hlW;  stride = 2;  colb = o; }
    else if (o < 7)  { Wc = intW; stride = 5;  colb = o - 2; }
    else             { Wc = actW; stride = 36; colb = o - 7; }
    float s = 0.f;
    #pragma unroll
    for (int q = 0; q < 16; ++q) {
      int m = lane + q * 64;
      s += feat[m] * Wc[(size_t)m * stride + colb];
    }
    #pragma unroll
    for (int d = 32; d >= 1; d >>= 1) s += __shfl_xor(s, d);
    if (lane == 0) {
      float res;
      if (o < 2)      res = s + hlb[o];
      else if (o < 7) res = s + intb[o - 2];
      else {
        int a = o - 7;
        float v = vm[a];
        res = __logf(v) + s * v + actb[a] * v;
      }
      out[o] = res;
    }
  }
}

extern "C" void kernel_launch(void* const* d_in, const int* in_sizes, int n_in,
                              void* d_out, int out_size, void* d_ws, size_t ws_size,
                              hipStream_t stream) {
  (void)in_sizes; (void)n_in; (void)d_ws; (void)ws_size; (void)out_size;
  const int* tokens   = (const int*)d_in[0];
  const float* vm     = (const float*)d_in[1];
  const float* Wiou_b = (const float*)d_in[2];
  const float* Uiou_b = (const float*)d_in[3];
  const float* biou_b = (const float*)d_in[4];
  const float* Wf_b   = (const float*)d_in[5];
  const float* Uf_b   = (const float*)d_in[6];
  const float* bf_b   = (const float*)d_in[7];
  const float* Wiou_t = (const float*)d_in[8];
  const float* Uiou_t = (const float*)d_in[9];
  const float* biou_t = (const float*)d_in[10];
  const float* Wf_t   = (const float*)d_in[11];
  const float* Uf_t   = (const float*)d_in[12];
  const float* bf_t   = (const float*)d_in[13];
  const float* ffnW   = (const float*)d_in[14];
  const float* ffnb   = (const float*)d_in[15];
  const float* lstmWx = (const float*)d_in[16];
  const float* lstmb  = (const float*)d_in[18];
  const float* hlW    = (const float*)d_in[19];
  const float* hlb    = (const float*)d_in[20];
  const float* intW   = (const float*)d_in[21];
  const float* intb   = (const float*)d_in[22];
  const float* actW   = (const float*)d_in[23];
  const float* actb   = (const float*)d_in[24];

  ushort_t* UiouT;  hipGetSymbolAddress((void**)&UiouT, HIP_SYMBOL(g_UiouT));
  ushort_t* UfT;    hipGetSymbolAddress((void**)&UfT, HIP_SYMBOL(g_UfT));
  ushort_t* UiouTt; hipGetSymbolAddress((void**)&UiouTt, HIP_SYMBOL(g_UiouTt));
  ushort_t* UfTt;   hipGetSymbolAddress((void**)&UfTt, HIP_SYMBOL(g_UfTt));

  // all 4 weight transposes in one launch
  k_transp_all<<<dim3(48, 48, 4), 256, 0, stream>>>(
      Uiou_b, Uf_b, Uiou_t, Uf_t, UiouT, UfT, UiouTt, UfTt);

  k_leaf<<<2048, 256, 0, stream>>>(tokens, Wiou_b, biou_b);
  for (int lvl = 13; lvl >= 8; --lvl) {
    int gx = (1 << lvl) / 128;
    k_mfma_lvl<<<dim3(gx, 8), 256, 0, stream>>>(lvl, tokens, Wiou_b, biou_b,
                                                Wf_b, bf_b);
  }
  for (int lvl = 7; lvl >= 0; --lvl) {
    int n = 1 << lvl;
    k_small<<<dim3(8, n), 256, 0, stream>>>(lvl, tokens, Wiou_b, biou_b,
                                            Wf_b, bf_b);
  }
  k_root_p1<<<dim3(12, 3), 256, 0, stream>>>();
  k_root_p2<<<1, 512, 0, stream>>>(tokens, Wiou_t, biou_t, Wf_t, bf_t);
  k_head1<<<1, 512, 0, stream>>>(ffnW, ffnb);
  k_head2<<<32, 64, 0, stream>>>(lstmWx, lstmb);
  k_head3<<<1, 512, 0, stream>>>(vm, hlW, hlb, intW, intb, actW, actb, (float*)d_out);
}

// Round 8
// 602.970 us; speedup vs baseline: 2.9088x; 1.0923x over previous
//
#include <hip/hip_runtime.h>
#include <hip/hip_bf16.h>
#include <math.h>

#define H 512
#define V 128
#define NLEAF 16384

typedef __attribute__((ext_vector_type(4))) float f32x4;
typedef __attribute__((ext_vector_type(8))) short s16x8;
typedef __attribute__((ext_vector_type(4))) unsigned short u16x4;
typedef unsigned short ushort_t;

// ---- static device scratch ----
__device__ ushort_t g_hb0[NLEAF * H];        // h bf16 (levels 14,12,...,0)
__device__ ushort_t g_hb1[(NLEAF / 2) * H];  // h bf16 (levels 13,11,...,1)
__device__ float    g_c0[NLEAF * H];         // c f32
__device__ float    g_c1[(NLEAF / 2) * H];
__device__ ushort_t g_UiouT[3 * H * 2 * H];  // [1536 cols][1024 k] bf16 (binary)
__device__ ushort_t g_UfT[H * 2 * H];        // [512 cols][1024 k] bf16 (f0|f1 halves)
__device__ ushort_t g_UiouTt[3 * H * 3 * H]; // [1536 cols][1536 k] bf16 (root)
__device__ ushort_t g_UfTt[H * 3 * H];       // [512 cols][1536 k] bf16 (f0|f1|f2)
__device__ float    g_rpart[3 * 3072];       // root k-chunk partials
__device__ float    g_root[2 * H];
__device__ float    g_hf[H];
__device__ float    g_gates[4 * H];

__device__ __forceinline__ float sigm(float x) { return 1.0f / (1.0f + __expf(-x)); }
__device__ __forceinline__ float ftanh(float x) {
  return 1.0f - 2.0f / (__expf(2.0f * x) + 1.0f);
}
__device__ __forceinline__ ushort_t f2bf(float x) {
  __hip_bfloat16 b = __float2bfloat16(x);
  return *reinterpret_cast<ushort_t*>(&b);
}
__device__ __forceinline__ float bf2f(ushort_t u) {
  union { unsigned int i; float f; } v; v.i = ((unsigned int)u) << 16; return v.f;
}
__device__ __forceinline__ void gload_lds16(const void* g, void* l) {
  __builtin_amdgcn_global_load_lds(
      (const __attribute__((address_space(1))) unsigned int*)g,
      (__attribute__((address_space(3))) unsigned int*)l, 16, 0, 0);
}

// ------- merged weight transpose+convert: 4 matrices in one launch --------
__global__ __launch_bounds__(256) void k_transp_all(
    const float* __restrict__ s0, const float* __restrict__ s1,
    const float* __restrict__ s2, const float* __restrict__ s3,
    ushort_t* __restrict__ d0, ushort_t* __restrict__ d1,
    ushort_t* __restrict__ d2, ushort_t* __restrict__ d3) {
  const float* src; ushort_t* dst; int R, Cc;
  switch (blockIdx.z) {
    case 0: src = s0; dst = d0; R = 1024; Cc = 1536; break;
    case 1: src = s1; dst = d1; R = 1024; Cc = 512; break;
    case 2: src = s2; dst = d2; R = 1536; Cc = 1536; break;
    default: src = s3; dst = d3; R = 1536; Cc = 512; break;
  }
  int bc = blockIdx.x * 32, br = blockIdx.y * 32;
  if (bc >= Cc || br >= R) return;
  __shared__ float t[32][33];
  int tx = threadIdx.x & 31, ty = threadIdx.x >> 5;  // 32 x 8
  for (int rr = ty; rr < 32; rr += 8)
    t[rr][tx] = src[(size_t)(br + rr) * Cc + bc + tx];
  __syncthreads();
  for (int rr = ty; rr < 32; rr += 8)
    dst[(size_t)(bc + rr) * R + br + tx] = f2bf(t[tx][rr]);
}

// ---------------- leaf level (lvl 14): hk = ck = 0, pure elementwise -------
__global__ __launch_bounds__(256) void k_leaf(const int* __restrict__ tokens,
                                              const float* __restrict__ Wiou,
                                              const float* __restrict__ biou) {
  const int total = NLEAF * 128;                    // quads
  for (int q = blockIdx.x * 256 + threadIdx.x; q < total; q += gridDim.x * 256) {
    int i = q >> 7, jv = q & 127;                   // jv = j/4
    int tok = tokens[(NLEAF - 1) + i];
    const f32x4* Wr = (const f32x4*)(Wiou + (size_t)tok * 1536);
    const f32x4* bv = (const f32x4*)biou;
    f32x4 wi = Wr[jv] + bv[jv];
    f32x4 wo = Wr[128 + jv] + bv[128 + jv];
    f32x4 wu = Wr[256 + jv] + bv[256 + jv];
    u16x4 hv; f32x4 cv;
    #pragma unroll
    for (int r = 0; r < 4; ++r) {
      float c = sigm(wi[r]) * ftanh(wu[r]);
      float h = sigm(wo[r]) * ftanh(c);
      cv[r] = c;
      hv[r] = f2bf(h);
    }
    *reinterpret_cast<u16x4*>(&g_hb0[(size_t)q * 4]) = hv;
    *reinterpret_cast<f32x4*>(&g_c0[(size_t)q * 4]) = cv;
  }
}

// ---------------- big levels (n >= 256): MFMA bf16 fused cell --------------
// 256 thr = 4 waves (2 row x 2 col). Tile: 128 nodes x 64 j-cols x 5 gates.
// Triple-buffered counted-vmcnt pipeline (T3/T4): loads for kt+1,kt+2 stay
// in flight across barriers; only kt's 6 loads must land (vmcnt(12)).
// LDS 72KB: A 3x8KB @0, B 3x16KB @24576. 2 blocks/CU.
__global__ __launch_bounds__(256, 2) void k_mfma_lvl(int lvl,
    const int* __restrict__ tokens,
    const float* __restrict__ Wiou, const float* __restrict__ biou,
    const float* __restrict__ Wf, const float* __restrict__ bf) {
  const int n = 1 << lvl;
  const int node0 = n - 1;
  const int outp = lvl & 1;
  const ushort_t* __restrict__ hprev = outp ? g_hb0 : g_hb1;
  const float* __restrict__ cprev = outp ? g_c0 : g_c1;
  ushort_t* __restrict__ hout = outp ? g_hb1 : g_hb0;
  float* __restrict__ cout = outp ? g_c1 : g_c0;

  const int i0 = blockIdx.x * 128;
  const int j0 = blockIdx.y * 64;
  const int tid = threadIdx.x;
  const int lane = tid & 63;
  const int w = tid >> 6;        // 0..3
  const int wry = w >> 1;        // row half
  const int cx = w & 1;          // col half

  __shared__ f32x4 smemv[4608];  // 72KB
  char* smem = (char*)smemv;

  const char* gp[6];
  unsigned lb[6], lstride[6];
  {
    int kb = (lane >> 4) * 16;
    #pragma unroll
    for (int q = 0; q < 6; ++q) {
      int c = w * 6 + q;
      if (c < 8) {               // A chunk, row-tile c
        int row = i0 + c * 16 + (lane & 15);
        gp[q] = (const char*)hprev + (size_t)row * 2048 + kb;
        lb[q] = c * 1024u;
        lstride[q] = 8192u;
      } else {                   // B chunk, col-tile ct
        int ct = c - 8;
        int col = ct * 16 + (lane & 15);
        int g = col >> 6, jj = j0 + (col & 63);
        const ushort_t* Ub = (g < 3) ? (g_UiouT + (size_t)(g * 512 + jj) * 1024)
                                     : (g_UfT + (size_t)jj * 1024);
        gp[q] = (const char*)Ub + kb;
        lb[q] = 24576u + ct * 1024u;
        lstride[q] = 16384u;
      }
    }
  }

#define STAGE(BUF)                                                   \
  {                                                                  \
    _Pragma("unroll")                                                \
    for (int q = 0; q < 6; ++q) {                                    \
      gload_lds16(gp[q], smem + lb[q] + (unsigned)(BUF) * lstride[q]); \
      gp[q] += 64;                                                   \
    }                                                                \
  }
#define WAITV(N) asm volatile("s_waitcnt vmcnt(" #N ")" ::: "memory")

  f32x4 acc[4][10];
  #pragma unroll
  for (int a = 0; a < 4; ++a)
    #pragma unroll
    for (int b = 0; b < 10; ++b) acc[a][b] = (f32x4){0.f, 0.f, 0.f, 0.f};

#define COMPUTE(FA)                                                          \
  {                                                                          \
    const char* ab = smem + buf * 8192 + wry * 4096 + lane * 16;             \
    s16x8 a0 = *(const s16x8*)(ab);                                          \
    s16x8 a1 = *(const s16x8*)(ab + 1024);                                   \
    s16x8 a2 = *(const s16x8*)(ab + 2048);                                   \
    s16x8 a3 = *(const s16x8*)(ab + 3072);                                   \
    const char* bb = smem + 24576 + buf * 16384 + cx * 2048 + lane * 16;     \
    s16x8 b0 = *(const s16x8*)(bb);                                          \
    s16x8 b1 = *(const s16x8*)(bb + 1024);                                   \
    s16x8 b2 = *(const s16x8*)(bb + 4096);                                   \
    s16x8 b3 = *(const s16x8*)(bb + 5120);                                   \
    s16x8 b4 = *(const s16x8*)(bb + 8192);                                   \
    s16x8 b5 = *(const s16x8*)(bb + 9216);                                   \
    s16x8 b6 = *(const s16x8*)(bb + 12288);                                  \
    s16x8 b7 = *(const s16x8*)(bb + 13312);                                  \
    s16x8 aa[4] = {a0, a1, a2, a3};                                          \
    _Pragma("unroll")                                                        \
    for (int rtl = 0; rtl < 4; ++rtl) {                                      \
      acc[rtl][0] = __builtin_amdgcn_mfma_f32_16x16x32_bf16(aa[rtl], b0, acc[rtl][0], 0, 0, 0); \
      acc[rtl][1] = __builtin_amdgcn_mfma_f32_16x16x32_bf16(aa[rtl], b1, acc[rtl][1], 0, 0, 0); \
      acc[rtl][2] = __builtin_amdgcn_mfma_f32_16x16x32_bf16(aa[rtl], b2, acc[rtl][2], 0, 0, 0); \
      acc[rtl][3] = __builtin_amdgcn_mfma_f32_16x16x32_bf16(aa[rtl], b3, acc[rtl][3], 0, 0, 0); \
      acc[rtl][4] = __builtin_amdgcn_mfma_f32_16x16x32_bf16(aa[rtl], b4, acc[rtl][4], 0, 0, 0); \
      acc[rtl][5] = __builtin_amdgcn_mfma_f32_16x16x32_bf16(aa[rtl], b5, acc[rtl][5], 0, 0, 0); \
      acc[rtl][FA] = __builtin_amdgcn_mfma_f32_16x16x32_bf16(aa[rtl], b6, acc[rtl][FA], 0, 0, 0); \
      acc[rtl][FA + 1] = __builtin_amdgcn_mfma_f32_16x16x32_bf16(aa[rtl], b7, acc[rtl][FA + 1], 0, 0, 0); \
    }                                                                        \
  }

  // prologue: stage kt=0,1,2 into buffers 0,1,2 (18 loads in flight)
  STAGE(0); STAGE(1); STAGE(2);
  int buf = 0;
  // main loop; stage kt+3 into the buffer just computed (same index mod 3).
  // barrier AFTER compute protects the overwrite; vmcnt(12) waits only for
  // this kt's 6 loads (12 newer ones stay in flight).
  for (int kt = 0; kt < 16; ++kt) {
    WAITV(12);
    __builtin_amdgcn_s_barrier();
    COMPUTE(6);
    __builtin_amdgcn_s_barrier();
    STAGE(buf);
    buf = (buf == 2) ? 0 : buf + 1;
  }
  for (int kt = 16; kt < 29; ++kt) {
    WAITV(12);
    __builtin_amdgcn_s_barrier();
    COMPUTE(8);
    __builtin_amdgcn_s_barrier();
    STAGE(buf);
    buf = (buf == 2) ? 0 : buf + 1;
  }
  // tail: kt=29,30,31 — no more staging; drain counted down
  WAITV(12); __builtin_amdgcn_s_barrier(); COMPUTE(8);
  buf = (buf == 2) ? 0 : buf + 1;
  WAITV(6);  __builtin_amdgcn_s_barrier(); COMPUTE(8);
  buf = (buf == 2) ? 0 : buf + 1;
  WAITV(0);  __builtin_amdgcn_s_barrier(); COMPUTE(8);
#undef COMPUTE
#undef STAGE
#undef WAITV

  const int node_c = lane >> 4;
  const int jl = lane & 15;
  #pragma unroll
  for (int t = 0; t < 2; ++t) {
    const int j = j0 + cx * 32 + t * 16 + jl;
    const float bi = biou[j], bo = biou[512 + j], bu = biou[1024 + j], bfv = bf[j];
    #pragma unroll
    for (int rtl = 0; rtl < 4; ++rtl) {
      f32x4 vi = acc[rtl][0 + t], vo = acc[rtl][2 + t], vu = acc[rtl][4 + t],
            v0 = acc[rtl][6 + t], v1 = acc[rtl][8 + t];
      const int ib = i0 + wry * 64 + rtl * 16 + node_c * 4;
      #pragma unroll
      for (int r = 0; r < 4; ++r) {
        int i = ib + r;
        int tok = tokens[node0 + i];
        const float* Wr = Wiou + (size_t)tok * 1536;
        float fpre = Wf[(size_t)tok * 512 + j] + bfv;
        float ig = vi[r] + Wr[j] + bi;
        float og = vo[r] + Wr[512 + j] + bo;
        float ug = vu[r] + Wr[1024 + j] + bu;
        float cc = sigm(ig) * ftanh(ug)
                 + sigm(fpre + v0[r]) * cprev[(size_t)(2 * i) * 512 + j]
                 + sigm(fpre + v1[r]) * cprev[(size_t)(2 * i + 1) * 512 + j];
        float hh = sigm(og) * ftanh(cc);
        hout[(size_t)i * 512 + j] = f2bf(hh);
        cout[(size_t)i * 512 + j] = cc;
      }
    }
  }
}

// ------------- small levels (n <= 128): single fused GEMV kernel -----------
__global__ __launch_bounds__(256) void k_small(int lvl,
    const int* __restrict__ tokens,
    const float* __restrict__ Wiou, const float* __restrict__ biou,
    const float* __restrict__ Wf, const float* __restrict__ bf) {
  const int n = 1 << lvl;
  const int node0 = n - 1;
  const int outp = lvl & 1;
  const ushort_t* __restrict__ hprev = outp ? g_hb0 : g_hb1;
  const float* __restrict__ cprev = outp ? g_c0 : g_c1;
  ushort_t* __restrict__ hout = outp ? g_hb1 : g_hb0;
  float* __restrict__ cout = outp ? g_c1 : g_c0;

  const int i = blockIdx.y;
  const int j0 = blockIdx.x * 64;
  const int tid = threadIdx.x;
  const int g = tid >> 6;
  const int jc = tid & 63;
  const int jj = j0 + jc;

  __shared__ float hl[1024];
  __shared__ float exch[5][64];
  for (int t = tid; t < 1024; t += 256) hl[t] = bf2f(hprev[(size_t)i * 1024 + t]);
  __syncthreads();

  const ushort_t* col = (g < 3) ? (g_UiouT + (size_t)(g * 512 + jj) * 1024)
                                : (g_UfT + (size_t)jj * 1024);
  float a0 = 0.f, a1 = 0.f;
  #pragma unroll 4
  for (int k0 = 0; k0 < 512; k0 += 8) {
    s16x8 wv = *(const s16x8*)(col + k0);
    #pragma unroll
    for (int r = 0; r < 8; ++r) a0 += hl[k0 + r] * bf2f((ushort_t)wv[r]);
  }
  #pragma unroll 4
  for (int k0 = 512; k0 < 1024; k0 += 8) {
    s16x8 wv = *(const s16x8*)(col + k0);
    #pragma unroll
    for (int r = 0; r < 8; ++r) a1 += hl[k0 + r] * bf2f((ushort_t)wv[r]);
  }
  if (g < 3) exch[g][jc] = a0 + a1;
  else { exch[3][jc] = a0; exch[4][jc] = a1; }
  __syncthreads();

  if (tid < 64) {
    int j = j0 + tid;
    float ai = exch[0][tid], ao = exch[1][tid], au = exch[2][tid];
    float af0 = exch[3][tid], af1 = exch[4][tid];
    int tok = tokens[node0 + i];
    const float* Wr = Wiou + (size_t)tok * 1536;
    float fpre = Wf[(size_t)tok * 512 + j] + bf[j];
    float ig = ai + Wr[j] + biou[j];
    float og = ao + Wr[512 + j] + biou[512 + j];
    float ug = au + Wr[1024 + j] + biou[1024 + j];
    float cc = sigm(ig) * ftanh(ug)
             + sigm(fpre + af0) * cprev[(size_t)(2 * i) * 512 + j]
             + sigm(fpre + af1) * cprev[(size_t)(2 * i + 1) * 512 + j];
    float hh = sigm(og) * ftanh(cc);
    hout[(size_t)i * 512 + j] = f2bf(hh);
    cout[(size_t)i * 512 + j] = cc;
  }
}

// ---------------- root ternary cell: 2-phase k-split -----------------------
__global__ __launch_bounds__(256) void k_root_p1() {
  const int by = blockIdx.y;
  const int tid = threadIdx.x;
  const int c = blockIdx.x * 256 + tid;      // 0..3071

  __shared__ float hl[512];
  {
    int m0 = by * 512;
    #pragma unroll
    for (int q = 0; q < 2; ++q) {
      int t = tid + q * 256, m = m0 + t;
      hl[t] = (m < 512) ? bf2f(g_hb0[m]) : bf2f(g_hb1[m - 512]);
    }
  }
  __syncthreads();

  float acc = 0.f;
  const ushort_t* col = nullptr;
  if (c < 1536) {
    col = g_UiouTt + (size_t)c * 1536 + by * 512;
  } else {
    int v = c - 1536;
    if ((v >> 9) == by) col = g_UfTt + (size_t)(v & 511) * 1536 + by * 512;
  }
  if (col) {
    #pragma unroll 4
    for (int k0 = 0; k0 < 512; k0 += 8) {
      s16x8 wv = *(const s16x8*)(col + k0);
      #pragma unroll
      for (int r = 0; r < 8; ++r) acc += hl[k0 + r] * bf2f((ushort_t)wv[r]);
    }
  }
  g_rpart[(size_t)by * 3072 + c] = acc;
}

__global__ __launch_bounds__(512) void k_root_p2(const int* __restrict__ tokens,
    const float* __restrict__ Wiou_t, const float* __restrict__ biou_t,
    const float* __restrict__ Wf_t, const float* __restrict__ bf_t) {
  const int j = threadIdx.x;
  float ai = g_rpart[j] + g_rpart[3072 + j] + g_rpart[6144 + j];
  float ao = g_rpart[512 + j] + g_rpart[3072 + 512 + j] + g_rpart[6144 + 512 + j];
  float au = g_rpart[1024 + j] + g_rpart[3072 + 1024 + j] + g_rpart[6144 + 1024 + j];
  float f0 = g_rpart[1536 + j] + g_rpart[3072 + 1536 + j] + g_rpart[6144 + 1536 + j];
  float f1 = g_rpart[2048 + j] + g_rpart[3072 + 2048 + j] + g_rpart[6144 + 2048 + j];
  float f2 = g_rpart[2560 + j] + g_rpart[3072 + 2560 + j] + g_rpart[6144 + 2560 + j];

  int tok = tokens[0];
  float fpre = Wf_t[(size_t)tok * H + j] + bf_t[j];
  float ig = ai + Wiou_t[(size_t)tok * 3 * H + j] + biou_t[j];
  float og = ao + Wiou_t[(size_t)tok * 3 * H + H + j] + biou_t[H + j];
  float ug = au + Wiou_t[(size_t)tok * 3 * H + 2 * H + j] + biou_t[2 * H + j];
  float cc = sigm(ig) * ftanh(ug)
           + sigm(fpre + f0) * g_c0[j]
           + sigm(fpre + f1) * g_c1[j]
           + sigm(fpre + f2) * g_c1[H + j];
  float hh = sigm(og) * ftanh(cc);
  g_root[j] = hh;
  g_root[H + j] = cc;
}

// ---------------- heads ----------------------------------------------------
__global__ __launch_bounds__(512) void k_head1(const float* __restrict__ ffnW,
                                               const float* __restrict__ ffnb) {
  __shared__ float hr[H];
  int j = threadIdx.x;
  hr[j] = g_root[j];
  __syncthreads();
  float acc = ffnb[j];
  #pragma unroll 8
  for (int m = 0; m < H; ++m) acc += hr[m] * ffnW[m * H + j];
  g_hf[j] = fmaxf(acc, 0.0f);
}

__global__ __launch_bounds__(64) void k_head2(const float* __restrict__ Wx,
                                              const float* __restrict__ lb) {
  int g = blockIdx.x * 64 + threadIdx.x;
  float acc = lb[g];
  #pragma unroll 8
  for (int m = 0; m < H; ++m) acc += g_hf[m] * Wx[m * 4 * H + g];
  g_gates[g] = acc;  // h_g starts at 0 so Wh term vanishes
}

__global__ __launch_bounds__(512) void k_head3(const float* __restrict__ vm,
    const float* __restrict__ hlW, const float* __restrict__ hlb,
    const float* __restrict__ intW, const float* __restrict__ intb,
    const float* __restrict__ actW, const float* __restrict__ actb,
    float* __restrict__ out) {
  __shared__ float feat[2 * H];
  int j = threadIdx.x;
  float ci = sigm(g_gates[j]) * ftanh(g_gates[2 * H + j]);
  float hg = sigm(g_gates[3 * H + j]) * ftanh(ci);
  feat[j] = g_hf[j];
  feat[H + j] = hg;
  __syncthreads();

  const int wv = threadIdx.x >> 6;
  const int lane = threadIdx.x & 63;
  for (int o = wv; o < 43; o += 8) {
    const float* Wc;
    int stride, colb;
    if (o < 2)       { Wc = hlW;  stride = 2;  colb = o; }
    else if (o < 7)  { Wc = intW; stride = 5;  colb = o - 2; }
    else             { Wc = actW; stride = 36; colb = o - 7; }
    float s = 0.f;
    #pragma unroll
    for (int q = 0; q < 16; ++q) {
      int m = lane + q * 64;
      s += feat[m] * Wc[(size_t)m * stride + colb];
    }
    #pragma unroll
    for (int d = 32; d >= 1; d >>= 1) s += __shfl_xor(s, d);
    if (lane == 0) {
      float res;
      if (o < 2)      res = s + hlb[o];
      else if (o < 7) res = s + intb[o - 2];
      else {
        int a = o - 7;
        float v = vm[a];
        res = __logf(v) + s * v + actb[a] * v;
      }
      out[o] = res;
    }
  }
}

extern "C" void kernel_launch(void* const* d_in, const int* in_sizes, int n_in,
                              void* d_out, int out_size, void* d_ws, size_t ws_size,
                              hipStream_t stream) {
  (void)in_sizes; (void)n_in; (void)d_ws; (void)ws_size; (void)out_size;
  const int* tokens   = (const int*)d_in[0];
  const float* vm     = (const float*)d_in[1];
  const float* Wiou_b = (const float*)d_in[2];
  const float* Uiou_b = (const float*)d_in[3];
  const float* biou_b = (const float*)d_in[4];
  const float* Wf_b   = (const float*)d_in[5];
  const float* Uf_b   = (const float*)d_in[6];
  const float* bf_b   = (const float*)d_in[7];
  const float* Wiou_t = (const float*)d_in[8];
  const float* Uiou_t = (const float*)d_in[9];
  const float* biou_t = (const float*)d_in[10];
  const float* Wf_t   = (const float*)d_in[11];
  const float* Uf_t   = (const float*)d_in[12];
  const float* bf_t   = (const float*)d_in[13];
  const float* ffnW   = (const float*)d_in[14];
  const float* ffnb   = (const float*)d_in[15];
  const float* lstmWx = (const float*)d_in[16];
  const float* lstmb  = (const float*)d_in[18];
  const float* hlW    = (const float*)d_in[19];
  const float* hlb    = (const float*)d_in[20];
  const float* intW   = (const float*)d_in[21];
  const float* intb   = (const float*)d_in[22];
  const float* actW   = (const float*)d_in[23];
  const float* actb   = (const float*)d_in[24];

  ushort_t* UiouT;  hipGetSymbolAddress((void**)&UiouT, HIP_SYMBOL(g_UiouT));
  ushort_t* UfT;    hipGetSymbolAddress((void**)&UfT, HIP_SYMBOL(g_UfT));
  ushort_t* UiouTt; hipGetSymbolAddress((void**)&UiouTt, HIP_SYMBOL(g_UiouTt));
  ushort_t* UfTt;   hipGetSymbolAddress((void**)&UfTt, HIP_SYMBOL(g_UfTt));

  // all 4 weight transposes in one launch
  k_transp_all<<<dim3(48, 48, 4), 256, 0, stream>>>(
      Uiou_b, Uf_b, Uiou_t, Uf_t, UiouT, UfT, UiouTt, UfTt);

  k_leaf<<<2048, 256, 0, stream>>>(tokens, Wiou_b, biou_b);
  for (int lvl = 13; lvl >= 8; --lvl) {
    int gx = (1 << lvl) / 128;
    k_mfma_lvl<<<dim3(gx, 8), 256, 0, stream>>>(lvl, tokens, Wiou_b, biou_b,
                                                Wf_b, bf_b);
  }
  for (int lvl = 7; lvl >= 0; --lvl) {
    int n = 1 << lvl;
    k_small<<<dim3(8, n), 256, 0, stream>>>(lvl, tokens, Wiou_b, biou_b,
                                            Wf_b, bf_b);
  }
  k_root_p1<<<dim3(12, 3), 256, 0, stream>>>();
  k_root_p2<<<1, 512, 0, stream>>>(tokens, Wiou_t, biou_t, Wf_t, bf_t);
  k_head1<<<1, 512, 0, stream>>>(ffnW, ffnb);
  k_head2<<<32, 64, 0, stream>>>(lstmWx, lstmb);
  k_head3<<<1, 512, 0, stream>>>(vm, hlW, hlb, intW, intb, actW, actb, (float*)d_out);
}